// Round 1
// baseline (2326.670 us; speedup 1.0000x reference)
//
#include <hip/hip_runtime.h>
#include <math.h>

#define H_ 56
#define W_ 56
#define CIN 256
#define COUT 256
#define NB 8
#define KTAPS 9
#define SPIX (H_*W_)          // 3136
#define KG (CIN*KTAPS)        // 2304
#define BM 64
#define BN 64
#define BK 32
#define AST 68                // At row stride (floats): mult of 4 -> 16B-aligned float4 rows
#define BST 68
#define CST 65

// ---------------- pre-kernel 1: NCHW -> NHWC transpose (per image: 256 x 3136 transpose)
__global__ __launch_bounds__(256) void transpose_nchw_nhwc(const float* __restrict__ x,
                                                           float* __restrict__ xt) {
    __shared__ float tile[64][65];
    const int n  = blockIdx.z;
    const int c0 = blockIdx.y * 64;
    const int s0 = blockIdx.x * 64;
    const int tid = threadIdx.x;
    const float* xb  = x  + (size_t)n * CIN * SPIX;
    float*       xtb = xt + (size_t)n * SPIX * CIN;
#pragma unroll
    for (int i = 0; i < 16; ++i) {
        int idx = tid + i * 256;
        int cr = idx >> 6, sc = idx & 63;
        tile[cr][sc] = xb[(size_t)(c0 + cr) * SPIX + s0 + sc];   // coalesced along s
    }
    __syncthreads();
#pragma unroll
    for (int i = 0; i < 16; ++i) {
        int idx = tid + i * 256;
        int sr = idx >> 6, cc = idx & 63;
        xtb[(size_t)(s0 + sr) * CIN + c0 + cc] = tile[cc][sr];   // coalesced along c
    }
}

// ---------------- pre-kernel 2: pack weight (Cout,Cin,3,3) -> Bp[kk= k*256+c][o]
__global__ __launch_bounds__(256) void pack_w(const float* __restrict__ w,
                                              float* __restrict__ bp) {
    const int kg = blockIdx.x;         // 0..2303
    const int k = kg >> 8, c = kg & 255;
    const int o = threadIdx.x;
    bp[(size_t)kg * COUT + o] = w[(size_t)o * KG + c * KTAPS + k];
}

// ---------------- main fused kernel: deformable-im2col producer + tiled SGEMM
__global__ __launch_bounds__(256) void mdcn_main(
    const float* __restrict__ xs,      // NHWC (fast) or NCHW (fallback)
    const float* __restrict__ offs,    // (N, 18, 56, 56)
    const float* __restrict__ msk,     // (N, 9, 56, 56)
    const float* __restrict__ bp,      // packed B or nullptr
    const float* __restrict__ wraw,    // raw weight (fallback)
    const float* __restrict__ bias,    // (256,)
    float* __restrict__ out,           // (N, 256, 56, 56)
    int nhwc)
{
    __shared__ float smem[BK * AST + BK * BST];   // 4352 floats; Cs overlays
    __shared__ int   sBase[4][BM];
    __shared__ float sWgt[4][BM];

    float (*At)[AST] = (float (*)[AST])smem;                    // At[BK][AST]: A^T tile
    float (*Bt)[BST] = (float (*)[BST])(smem + BK * AST);       // Bt[BK][BST]
    float (*Cs)[CST] = (float (*)[CST])smem;                    // Cs[BM][CST] (epilogue reuse)

    const int tid = threadIdx.x;
    const int m0 = blockIdx.x * BM;          // pixel tile base (3136 % 64 == 0 -> single n)
    const int o0 = blockIdx.y * BN;          // cout tile base
    const int n  = m0 / SPIX;
    const int s0 = m0 - n * SPIX;
    const int cstride = nhwc ? 1 : SPIX;

    const int tx = tid & 15, ty = tid >> 4;
    float acc[4][4] = {};

    for (int k = 0; k < KTAPS; ++k) {
        // ---- per-(pixel,k) bilinear params: 4 tap bases + 4 folded weights (mask, validity)
        if (tid < BM) {
            const int s = s0 + tid;
            const int h = s / W_;
            const int w = s - h * W_;
            const int kY = k / 3, kX = k - kY * 3;
            const float dy = offs[(size_t)n * (2 * KTAPS * SPIX) + (size_t)(2 * k) * SPIX + s];
            const float dx = offs[(size_t)n * (2 * KTAPS * SPIX) + (size_t)(2 * k + 1) * SPIX + s];
            const float mk = msk[(size_t)n * (KTAPS * SPIX) + (size_t)k * SPIX + s];
            const float py = dy + (float)(kY + h - 1);   // PAD=1, STRIDE=1, DIL=1
            const float px = dx + (float)(kX + w - 1);
            const float fy0 = floorf(py), fx0 = floorf(px);
            const int y0 = (int)fy0, x0 = (int)fx0;
            const float wy1 = py - fy0, wx1 = px - fx0;
            const float wy0 = 1.0f - wy1, wx0 = 1.0f - wx1;
#pragma unroll
            for (int t = 0; t < 4; ++t) {
                const int yi = y0 + (t >> 1);
                const int xi = x0 + (t & 1);
                const bool valid = (yi >= 0) & (yi < H_) & (xi >= 0) & (xi < W_);
                const int yc = min(max(yi, 0), H_ - 1);
                const int xc = min(max(xi, 0), W_ - 1);
                float wt = ((t >> 1) ? wy1 : wy0) * ((t & 1) ? wx1 : wx0) * mk;
                int base;
                if (nhwc) base = (n * SPIX + yc * W_ + xc) * CIN;
                else      base = n * (CIN * SPIX) + yc * W_ + xc;
                sBase[t][tid] = base;
                sWgt[t][tid] = valid ? wt : 0.0f;
            }
        }
        __syncthreads();

        for (int c0 = 0; c0 < CIN; c0 += BK) {
            // ---- stage A^T tile: At[cc][row] = bilinear sample (pixel=row, chan=c0+cc, tap k)
#pragma unroll
            for (int i = 0; i < 8; ++i) {
                int idx = tid + i * 256;
                int row = idx >> 5, cc = idx & 31;
                int ce = (c0 + cc) * cstride;
                float v = sWgt[0][row] * xs[sBase[0][row] + ce]
                        + sWgt[1][row] * xs[sBase[1][row] + ce]
                        + sWgt[2][row] * xs[sBase[2][row] + ce]
                        + sWgt[3][row] * xs[sBase[3][row] + ce];
                At[cc][row] = v;
            }
            // ---- stage B tile
            if (bp) {
#pragma unroll
                for (int i = 0; i < 8; ++i) {
                    int idx = tid + i * 256;
                    int kk = idx >> 6, o = idx & 63;
                    Bt[kk][o] = bp[(size_t)(k * CIN + c0 + kk) * COUT + o0 + o];
                }
            } else {
#pragma unroll
                for (int i = 0; i < 8; ++i) {
                    int idx = tid + i * 256;
                    int kk = idx >> 6, o = idx & 63;
                    Bt[kk][o] = wraw[(size_t)(o0 + o) * KG + (c0 + kk) * KTAPS + k];
                }
            }
            __syncthreads();

            // ---- 4x4 micro-tile FMA
#pragma unroll
            for (int kk = 0; kk < BK; ++kk) {
                const float4 a = *(const float4*)&At[kk][ty * 4];
                const float4 b = *(const float4*)&Bt[kk][tx * 4];
                acc[0][0] = fmaf(a.x, b.x, acc[0][0]);
                acc[0][1] = fmaf(a.x, b.y, acc[0][1]);
                acc[0][2] = fmaf(a.x, b.z, acc[0][2]);
                acc[0][3] = fmaf(a.x, b.w, acc[0][3]);
                acc[1][0] = fmaf(a.y, b.x, acc[1][0]);
                acc[1][1] = fmaf(a.y, b.y, acc[1][1]);
                acc[1][2] = fmaf(a.y, b.z, acc[1][2]);
                acc[1][3] = fmaf(a.y, b.w, acc[1][3]);
                acc[2][0] = fmaf(a.z, b.x, acc[2][0]);
                acc[2][1] = fmaf(a.z, b.y, acc[2][1]);
                acc[2][2] = fmaf(a.z, b.z, acc[2][2]);
                acc[2][3] = fmaf(a.z, b.w, acc[2][3]);
                acc[3][0] = fmaf(a.w, b.x, acc[3][0]);
                acc[3][1] = fmaf(a.w, b.y, acc[3][1]);
                acc[3][2] = fmaf(a.w, b.z, acc[3][2]);
                acc[3][3] = fmaf(a.w, b.w, acc[3][3]);
            }
            __syncthreads();
        }
    }

    // ---- epilogue: stage C in LDS (aliases At/Bt — safe after final barrier), coalesced NCHW store
#pragma unroll
    for (int i = 0; i < 4; ++i)
#pragma unroll
        for (int j = 0; j < 4; ++j)
            Cs[ty * 4 + i][tx * 4 + j] = acc[i][j] + bias[o0 + tx * 4 + j];
    __syncthreads();

    const int pix = tid & 63;
    const int ob  = tid >> 6;
    float* outp = out + (size_t)n * COUT * SPIX + s0 + pix;
#pragma unroll
    for (int r = 0; r < 16; ++r) {
        int o = r * 4 + ob;
        outp[(size_t)(o0 + o) * SPIX] = Cs[pix][o];
    }
}

extern "C" void kernel_launch(void* const* d_in, const int* in_sizes, int n_in,
                              void* d_out, int out_size, void* d_ws, size_t ws_size,
                              hipStream_t stream) {
    const float* x    = (const float*)d_in[0];
    const float* offs = (const float*)d_in[1];
    const float* msk  = (const float*)d_in[2];
    const float* w    = (const float*)d_in[3];
    const float* bias = (const float*)d_in[4];
    float* out = (float*)d_out;

    const size_t xt_bytes = (size_t)NB * SPIX * CIN * sizeof(float);   // 25.7 MB
    const size_t bp_bytes = (size_t)KG * COUT * sizeof(float);         // 2.36 MB
    const bool use_ws = ws_size >= xt_bytes + bp_bytes;

    if (use_ws) {
        float* xt = (float*)d_ws;
        float* bp = (float*)((char*)d_ws + xt_bytes);
        transpose_nchw_nhwc<<<dim3(49, 4, 8), 256, 0, stream>>>(x, xt);
        pack_w<<<dim3(KG), 256, 0, stream>>>(w, bp);
        mdcn_main<<<dim3(NB * SPIX / BM, COUT / BN), 256, 0, stream>>>(
            xt, offs, msk, bp, w, bias, out, 1);
    } else {
        // fallback: direct NCHW gathers + raw weight reads (slower, still correct)
        mdcn_main<<<dim3(NB * SPIX / BM, COUT / BN), 256, 0, stream>>>(
            x, offs, msk, nullptr, w, bias, out, 0);
    }
}

// Round 3
// 234.743 us; speedup vs baseline: 9.9116x; 9.9116x over previous
//
#include <hip/hip_runtime.h>
#include <math.h>

#define H_ 56
#define W_ 56
#define CIN 256
#define COUT 256
#define NB 8
#define SPIX 3136
#define KG 2304
#define MTOT 25088

typedef __bf16 v8bf __attribute__((ext_vector_type(8)));
typedef float  v4f  __attribute__((ext_vector_type(4)));

// ---------- pre-kernel 1: NCHW fp32 -> NHWC bf16
__global__ __launch_bounds__(256) void prep_x(const float* __restrict__ x,
                                              __bf16* __restrict__ xb) {
    __shared__ float tile[64][65];
    const int n = blockIdx.z, c0 = blockIdx.y * 64, s0 = blockIdx.x * 64;
    const int tid = threadIdx.x;
    const float* xp = x + (size_t)n * CIN * SPIX;
    __bf16* xo = xb + (size_t)n * SPIX * CIN;
#pragma unroll
    for (int i = 0; i < 16; ++i) {
        int idx = tid + i * 256;
        int cr = idx >> 6, sc = idx & 63;
        tile[cr][sc] = xp[(c0 + cr) * SPIX + s0 + sc];
    }
    __syncthreads();
#pragma unroll
    for (int i = 0; i < 16; ++i) {
        int idx = tid + i * 256;
        int sr = idx >> 6, cc = idx & 63;
        xo[(s0 + sr) * CIN + c0 + cc] = (__bf16)tile[cc][sr];
    }
}

// ---------- pre-kernel 2: weight (Cout,Cin,3,3) fp32 -> Bp[o][tap*256+c] bf16
// one thread per element; trivially verifiable indexing
__global__ __launch_bounds__(256) void prep_w(const float* __restrict__ w,
                                              __bf16* __restrict__ bp) {
    const int i = blockIdx.x * 256 + threadIdx.x;     // 0 .. 589823
    if (i < COUT * KG) {
        const int o = i / KG;
        const int rem = i - o * KG;
        const int c = rem / 9;
        const int tap = rem - c * 9;
        bp[(size_t)o * KG + tap * 256 + c] = (__bf16)w[i];
    }
}

// ---------- main: fused deformable producer + bf16 MFMA GEMM
// 256 thr = 4 waves; block tile 128(pixels) x 128(couts); wave tile 64x64.
// tap-outer loop: params (4 tap bases + folded weights incl. mask/validity)
// computed once per tap by threads 0..127 into LDS, then register-cached.
__global__ __launch_bounds__(256, 3) void mdcn_mfma(
    const __bf16* __restrict__ xb,     // NHWC bf16
    const float*  __restrict__ offs,   // (N,18,56,56)
    const float*  __restrict__ msk,    // (N,9,56,56)
    const __bf16* __restrict__ bp,     // Bp[o][tap*256+c]
    const float*  __restrict__ bias,
    float*        __restrict__ out)    // (N,256,56,56)
{
    __shared__ __align__(16) char smem[20480];
    __bf16* Alds  = (__bf16*)smem;                 // [128][40] bf16 = 10240 B
    int*    sBase = (int*)(smem + 10240);          // [4][128]  = 2048 B
    float*  sWgt  = (float*)(smem + 12288);        // [4][128]  = 2048 B

    const int tid  = threadIdx.x;
    const int lane = tid & 63, wv = tid >> 6;
    const int wm = wv & 1, wn = wv >> 1;
    const int m0 = blockIdx.x * 128, o0 = blockIdx.y * 128;
    const int l15 = lane & 15, q = lane >> 4;
    const int prow = tid >> 2, pcg = tid & 3;      // producer: pixel rows {prow, prow+64}, chan chunk pcg

    v4f acc[4][4];
#pragma unroll
    for (int i = 0; i < 4; ++i)
#pragma unroll
        for (int j = 0; j < 4; ++j) acc[i][j] = (v4f)0.f;

    for (int tap = 0; tap < 9; ++tap) {
        // ---- per-tap bilinear params -> LDS (one pixel per thread, threads 0..127)
        if (tid < 128) {
            const int pg = m0 + tid;
            const int n  = pg / SPIX;
            const int s  = pg - n * SPIX;
            const int h  = s / W_;
            const int w  = s - h * W_;
            const int kY = tap / 3, kX = tap - kY * 3;
            const float dy = offs[n * (18 * SPIX) + (2 * tap) * SPIX + s];
            const float dx = offs[n * (18 * SPIX) + (2 * tap + 1) * SPIX + s];
            const float mk = msk[n * (9 * SPIX) + tap * SPIX + s];
            const float py = dy + (float)(kY + h - 1);   // PAD=1, STRIDE=1, DIL=1
            const float px = dx + (float)(kX + w - 1);
            const float fy0 = floorf(py), fx0 = floorf(px);
            const int y0 = (int)fy0, x0 = (int)fx0;
            const float wy1 = py - fy0, wx1 = px - fx0;
            const float wy0 = 1.0f - wy1, wx0 = 1.0f - wx1;
#pragma unroll
            for (int t = 0; t < 4; ++t) {
                const int yi = y0 + (t >> 1), xi = x0 + (t & 1);
                const bool valid = (yi >= 0) & (yi < H_) & (xi >= 0) & (xi < W_);
                const int yc = min(max(yi, 0), H_ - 1);
                const int xc = min(max(xi, 0), W_ - 1);
                sBase[t * 128 + tid] = (n * SPIX + yc * W_ + xc) * CIN;
                sWgt [t * 128 + tid] = valid
                    ? (((t >> 1) ? wy1 : wy0) * ((t & 1) ? wx1 : wx0) * mk) : 0.0f;
            }
        }
        __syncthreads();   // params ready (prior tap fully consumed at its last barrier)

        int   cb0[4], cb1[4];
        float cw0[4], cw1[4];
#pragma unroll
        for (int t = 0; t < 4; ++t) {
            cb0[t] = sBase[t * 128 + prow];
            cw0[t] = sWgt [t * 128 + prow];
            cb1[t] = sBase[t * 128 + prow + 64];
            cw1[t] = sWgt [t * 128 + prow + 64];
        }

        for (int c8 = 0; c8 < 8; ++c8) {
            const int kk  = tap * 8 + c8;
            const int cch = c8 * 32 + pcg * 8;

            // ---- produce A tile rows prow / prow+64, channels [c8*32+pcg*8, +8)
            {
                v8bf a0 = *(const v8bf*)(xb + cb0[0] + cch);
                v8bf a1 = *(const v8bf*)(xb + cb0[1] + cch);
                v8bf a2 = *(const v8bf*)(xb + cb0[2] + cch);
                v8bf a3 = *(const v8bf*)(xb + cb0[3] + cch);
                v8bf r;
#pragma unroll
                for (int j = 0; j < 8; ++j)
                    r[j] = (__bf16)(cw0[0] * (float)a0[j] + cw0[1] * (float)a1[j]
                                  + cw0[2] * (float)a2[j] + cw0[3] * (float)a3[j]);
                *(v8bf*)(Alds + prow * 40 + pcg * 8) = r;
            }
            {
                v8bf a0 = *(const v8bf*)(xb + cb1[0] + cch);
                v8bf a1 = *(const v8bf*)(xb + cb1[1] + cch);
                v8bf a2 = *(const v8bf*)(xb + cb1[2] + cch);
                v8bf a3 = *(const v8bf*)(xb + cb1[3] + cch);
                v8bf r;
#pragma unroll
                for (int j = 0; j < 8; ++j)
                    r[j] = (__bf16)(cw1[0] * (float)a0[j] + cw1[1] * (float)a1[j]
                                  + cw1[2] * (float)a2[j] + cw1[3] * (float)a3[j]);
                *(v8bf*)(Alds + (prow + 64) * 40 + pcg * 8) = r;
            }

            // ---- B frags direct from global (B^T layout, L2-resident)
            v8bf bfr[4];
#pragma unroll
            for (int nt = 0; nt < 4; ++nt)
                bfr[nt] = *(const v8bf*)(bp
                    + (size_t)(o0 + wn * 64 + nt * 16 + l15) * KG + kk * 32 + q * 8);

            __syncthreads();               // A tile ready

            v8bf afr[4];
#pragma unroll
            for (int mt = 0; mt < 4; ++mt)
                afr[mt] = *(const v8bf*)(Alds + (wm * 64 + mt * 16 + l15) * 40 + q * 8);
#pragma unroll
            for (int mt = 0; mt < 4; ++mt)
#pragma unroll
                for (int nt = 0; nt < 4; ++nt)
                    acc[mt][nt] = __builtin_amdgcn_mfma_f32_16x16x32_bf16(
                        afr[mt], bfr[nt], acc[mt][nt], 0, 0, 0);

            __syncthreads();               // consume done; next produce / param write safe
        }
    }

    // ---- epilogue: per-wave 64x64 LDS transpose (stride 20 fp32), coalesced NCHW stores
    float* epi = (float*)smem + wv * (64 * 20);
    const int pg = m0 + wm * 64 + lane;    // 64-aligned span; SPIX % 64 == 0 -> single image
    const int n_img = pg / SPIX;
    const int s_pix = pg - n_img * SPIX;
    float* outb = out + (size_t)n_img * COUT * SPIX + s_pix;

#pragma unroll
    for (int nt = 0; nt < 4; ++nt) {
        const float bv = bias[o0 + wn * 64 + nt * 16 + l15];
#pragma unroll
        for (int mt = 0; mt < 4; ++mt)
#pragma unroll
            for (int r = 0; r < 4; ++r)
                epi[(mt * 16 + q * 4 + r) * 20 + l15] = acc[mt][nt][r] + bv;
        __syncthreads();
#pragma unroll
        for (int c4 = 0; c4 < 4; ++c4) {
            v4f vv = *(const v4f*)(epi + lane * 20 + c4 * 4);
            const int ob = o0 + wn * 64 + nt * 16 + c4 * 4;
            outb[(size_t)(ob + 0) * SPIX] = vv.x;
            outb[(size_t)(ob + 1) * SPIX] = vv.y;
            outb[(size_t)(ob + 2) * SPIX] = vv.z;
            outb[(size_t)(ob + 3) * SPIX] = vv.w;
        }
        __syncthreads();
    }
}

// ---------- fallback (round-1 verified fp32 path, no workspace needed)
#define BM 64
#define BN 64
#define BKF 32
#define AST 68
#define BST 68
#define CST 65
__global__ __launch_bounds__(256) void mdcn_fallback(
    const float* __restrict__ xs, const float* __restrict__ offs,
    const float* __restrict__ msk, const float* __restrict__ wraw,
    const float* __restrict__ bias, float* __restrict__ out)
{
    __shared__ float smem[BKF * AST + BKF * BST];
    __shared__ int   sBase[4][BM];
    __shared__ float sWgt[4][BM];
    float (*At)[AST] = (float (*)[AST])smem;
    float (*Bt)[BST] = (float (*)[BST])(smem + BKF * AST);
    float (*Cs)[CST] = (float (*)[CST])smem;
    const int tid = threadIdx.x;
    const int m0 = blockIdx.x * BM;
    const int o0 = blockIdx.y * BN;
    const int n  = m0 / SPIX;
    const int s0 = m0 - n * SPIX;
    const int tx = tid & 15, ty = tid >> 4;
    float acc[4][4] = {};
    for (int k = 0; k < 9; ++k) {
        if (tid < BM) {
            const int s = s0 + tid;
            const int h = s / W_;
            const int w = s - h * W_;
            const int kY = k / 3, kX = k - kY * 3;
            const float dy = offs[(size_t)n * (18 * SPIX) + (size_t)(2 * k) * SPIX + s];
            const float dx = offs[(size_t)n * (18 * SPIX) + (size_t)(2 * k + 1) * SPIX + s];
            const float mk = msk[(size_t)n * (9 * SPIX) + (size_t)k * SPIX + s];
            const float py = dy + (float)(kY + h - 1);
            const float px = dx + (float)(kX + w - 1);
            const float fy0 = floorf(py), fx0 = floorf(px);
            const int y0 = (int)fy0, x0 = (int)fx0;
            const float wy1 = py - fy0, wx1 = px - fx0;
            const float wy0 = 1.0f - wy1, wx0 = 1.0f - wx1;
#pragma unroll
            for (int t = 0; t < 4; ++t) {
                const int yi = y0 + (t >> 1), xi = x0 + (t & 1);
                const bool valid = (yi >= 0) & (yi < H_) & (xi >= 0) & (xi < W_);
                const int yc = min(max(yi, 0), H_ - 1);
                const int xc = min(max(xi, 0), W_ - 1);
                float wt = ((t >> 1) ? wy1 : wy0) * ((t & 1) ? wx1 : wx0) * mk;
                sBase[t][tid] = n * (CIN * SPIX) + yc * W_ + xc;
                sWgt[t][tid] = valid ? wt : 0.0f;
            }
        }
        __syncthreads();
        for (int c0 = 0; c0 < CIN; c0 += BKF) {
#pragma unroll
            for (int i = 0; i < 8; ++i) {
                int idx = tid + i * 256;
                int row = idx >> 5, cc = idx & 31;
                int ce = (c0 + cc) * SPIX;
                At[cc][row] = sWgt[0][row] * xs[sBase[0][row] + ce]
                            + sWgt[1][row] * xs[sBase[1][row] + ce]
                            + sWgt[2][row] * xs[sBase[2][row] + ce]
                            + sWgt[3][row] * xs[sBase[3][row] + ce];
            }
#pragma unroll
            for (int i = 0; i < 8; ++i) {
                int idx = tid + i * 256;
                int kf = idx >> 6, o = idx & 63;
                Bt[kf][o] = wraw[(size_t)(o0 + o) * KG + (c0 + kf) * 9 + k];
            }
            __syncthreads();
#pragma unroll
            for (int kf = 0; kf < BKF; ++kf) {
                const float4 a = *(const float4*)&At[kf][ty * 4];
                const float4 b = *(const float4*)&Bt[kf][tx * 4];
                acc[0][0] = fmaf(a.x, b.x, acc[0][0]); acc[0][1] = fmaf(a.x, b.y, acc[0][1]);
                acc[0][2] = fmaf(a.x, b.z, acc[0][2]); acc[0][3] = fmaf(a.x, b.w, acc[0][3]);
                acc[1][0] = fmaf(a.y, b.x, acc[1][0]); acc[1][1] = fmaf(a.y, b.y, acc[1][1]);
                acc[1][2] = fmaf(a.y, b.z, acc[1][2]); acc[1][3] = fmaf(a.y, b.w, acc[1][3]);
                acc[2][0] = fmaf(a.z, b.x, acc[2][0]); acc[2][1] = fmaf(a.z, b.y, acc[2][1]);
                acc[2][2] = fmaf(a.z, b.z, acc[2][2]); acc[2][3] = fmaf(a.z, b.w, acc[2][3]);
                acc[3][0] = fmaf(a.w, b.x, acc[3][0]); acc[3][1] = fmaf(a.w, b.y, acc[3][1]);
                acc[3][2] = fmaf(a.w, b.z, acc[3][2]); acc[3][3] = fmaf(a.w, b.w, acc[3][3]);
            }
            __syncthreads();
        }
    }
#pragma unroll
    for (int i = 0; i < 4; ++i)
#pragma unroll
        for (int j = 0; j < 4; ++j)
            Cs[ty * 4 + i][tx * 4 + j] = acc[i][j] + bias[o0 + tx * 4 + j];
    __syncthreads();
    const int pix = tid & 63, ob = tid >> 6;
    float* outp = out + (size_t)n * COUT * SPIX + s0 + pix;
#pragma unroll
    for (int r = 0; r < 16; ++r) {
        int o = r * 4 + ob;
        outp[(size_t)(o0 + o) * SPIX] = Cs[pix][o];
    }
}

extern "C" void kernel_launch(void* const* d_in, const int* in_sizes, int n_in,
                              void* d_out, int out_size, void* d_ws, size_t ws_size,
                              hipStream_t stream) {
    const float* x    = (const float*)d_in[0];
    const float* offs = (const float*)d_in[1];
    const float* msk  = (const float*)d_in[2];
    const float* w    = (const float*)d_in[3];
    const float* bias = (const float*)d_in[4];
    float* out = (float*)d_out;

    const size_t xb_bytes = (size_t)NB * SPIX * CIN * sizeof(__bf16);   // 12.85 MB
    const size_t bp_bytes = (size_t)KG * COUT * sizeof(__bf16);         // 1.18 MB

    if (ws_size >= xb_bytes + bp_bytes) {
        __bf16* xb = (__bf16*)d_ws;
        __bf16* bp = (__bf16*)((char*)d_ws + xb_bytes);
        prep_x<<<dim3(49, 4, 8), 256, 0, stream>>>(x, xb);
        prep_w<<<dim3((COUT * KG + 255) / 256), 256, 0, stream>>>(w, bp);
        mdcn_mfma<<<dim3(MTOT / 128, COUT / 128), 256, 0, stream>>>(
            xb, offs, msk, bp, bias, out);
    } else {
        mdcn_fallback<<<dim3(MTOT / BM, COUT / BN), 256, 0, stream>>>(
            x, offs, msk, w, bias, out);
    }
}

// Round 4
// 233.489 us; speedup vs baseline: 9.9648x; 1.0054x over previous
//
#include <hip/hip_runtime.h>
#include <math.h>

#define H_ 56
#define W_ 56
#define CIN 256
#define COUT 256
#define NB 8
#define SPIX 3136
#define KG 2304
#define MTOT 25088

typedef __bf16 v8bf __attribute__((ext_vector_type(8)));
typedef float  v4f  __attribute__((ext_vector_type(4)));

// ---------- pre-kernel 1: NCHW fp32 -> NHWC bf16
__global__ __launch_bounds__(256) void prep_x(const float* __restrict__ x,
                                              __bf16* __restrict__ xb) {
    __shared__ float tile[64][65];
    const int n = blockIdx.z, c0 = blockIdx.y * 64, s0 = blockIdx.x * 64;
    const int tid = threadIdx.x;
    const float* xp = x + (size_t)n * CIN * SPIX;
    __bf16* xo = xb + (size_t)n * SPIX * CIN;
#pragma unroll
    for (int i = 0; i < 16; ++i) {
        int idx = tid + i * 256;
        int cr = idx >> 6, sc = idx & 63;
        tile[cr][sc] = xp[(c0 + cr) * SPIX + s0 + sc];
    }
    __syncthreads();
#pragma unroll
    for (int i = 0; i < 16; ++i) {
        int idx = tid + i * 256;
        int sr = idx >> 6, cc = idx & 63;
        xo[(s0 + sr) * CIN + c0 + cc] = (__bf16)tile[cc][sr];
    }
}

// ---------- pre-kernel 2: weight (Cout,Cin,3,3) fp32 -> Bp[o][tap*256+c] bf16
__global__ __launch_bounds__(256) void prep_w(const float* __restrict__ w,
                                              __bf16* __restrict__ bp) {
    const int i = blockIdx.x * 256 + threadIdx.x;
    if (i < COUT * KG) {
        const int o = i / KG;
        const int rem = i - o * KG;
        const int c = rem / 9;
        const int tap = rem - c * 9;
        bp[(size_t)o * KG + tap * 256 + c] = (__bf16)w[i];
    }
}

// ---------- main: fused deformable producer + bf16 MFMA GEMM, split-K x2
// 256 thr = 4 waves; block tile 128(pixels) x 128(couts); wave tile 64x64.
// blockIdx.z selects tap half {0..4} / {5..8}. A tile double-buffered in LDS
// (1 barrier/K-step); next K-step's gathers register-prefetched.
__global__ __launch_bounds__(256, 3) void mdcn_mfma(
    const __bf16* __restrict__ xb,     // NHWC bf16
    const float*  __restrict__ offs,   // (N,18,56,56)
    const float*  __restrict__ msk,    // (N,9,56,56)
    const __bf16* __restrict__ bp,     // Bp[o][tap*256+c]
    const float*  __restrict__ bias,
    float*        __restrict__ out)    // (N,256,56,56), pre-zeroed; atomic accum
{
    __shared__ __align__(16) char smem[24576];
    __bf16* A0 = (__bf16*)smem;                    // [128][40] bf16 = 10240 B
    __bf16* A1 = (__bf16*)(smem + 10240);          // double buffer
    int*    sBase = (int*)(smem + 20480);          // [4][128]
    float*  sWgt  = (float*)(smem + 22528);        // [4][128]

    const int tid  = threadIdx.x;
    const int lane = tid & 63, wv = tid >> 6;
    const int wm = wv & 1, wn = wv >> 1;
    const int m0 = blockIdx.x * 128, o0 = blockIdx.y * 128;
    const int kz = blockIdx.z;
    const int tap_lo = kz ? 5 : 0, tap_hi = kz ? 9 : 5;
    const int l15 = lane & 15, q = lane >> 4;
    const int prow = tid >> 2, pcg = tid & 3;

    v4f acc[4][4];
#pragma unroll
    for (int i = 0; i < 4; ++i)
#pragma unroll
        for (int j = 0; j < 4; ++j) acc[i][j] = (v4f)0.f;

    for (int tap = tap_lo; tap < tap_hi; ++tap) {
        // ---- per-tap bilinear params -> LDS (threads 0..127, one pixel each)
        if (tid < 128) {
            const int pg = m0 + tid;
            const int n  = pg / SPIX;
            const int s  = pg - n * SPIX;
            const int h  = s / W_;
            const int w  = s - h * W_;
            const int kY = tap / 3, kX = tap - kY * 3;
            const float dy = offs[n * (18 * SPIX) + (2 * tap) * SPIX + s];
            const float dx = offs[n * (18 * SPIX) + (2 * tap + 1) * SPIX + s];
            const float mk = msk[n * (9 * SPIX) + tap * SPIX + s];
            const float py = dy + (float)(kY + h - 1);   // PAD=1,STRIDE=1,DIL=1
            const float px = dx + (float)(kX + w - 1);
            const float fy0 = floorf(py), fx0 = floorf(px);
            const int y0 = (int)fy0, x0 = (int)fx0;
            const float wy1 = py - fy0, wx1 = px - fx0;
            const float wy0 = 1.0f - wy1, wx0 = 1.0f - wx1;
#pragma unroll
            for (int t = 0; t < 4; ++t) {
                const int yi = y0 + (t >> 1), xi = x0 + (t & 1);
                const bool valid = (yi >= 0) & (yi < H_) & (xi >= 0) & (xi < W_);
                const int yc = min(max(yi, 0), H_ - 1);
                const int xc = min(max(xi, 0), W_ - 1);
                sBase[t * 128 + tid] = (n * SPIX + yc * W_ + xc) * CIN;
                sWgt [t * 128 + tid] = valid
                    ? (((t >> 1) ? wy1 : wy0) * ((t & 1) ? wx1 : wx0) * mk) : 0.0f;
            }
        }
        __syncthreads();   // params ready (prev tap's A-reads also complete)

        int   cb0[4], cb1[4];
        float cw0[4], cw1[4];
#pragma unroll
        for (int t = 0; t < 4; ++t) {
            cb0[t] = sBase[t * 128 + prow];
            cw0[t] = sWgt [t * 128 + prow];
            cb1[t] = sBase[t * 128 + prow + 64];
            cw1[t] = sWgt [t * 128 + prow + 64];
        }

        // prologue gathers for c8 = 0
        v8bf rv[8];
        {
            const int cch = pcg * 8;
#pragma unroll
            for (int t = 0; t < 4; ++t) {
                rv[t]     = *(const v8bf*)(xb + cb0[t] + cch);
                rv[4 + t] = *(const v8bf*)(xb + cb1[t] + cch);
            }
        }

#pragma unroll
        for (int c8 = 0; c8 < 8; ++c8) {
            const int kk = tap * 8 + c8;
            __bf16* Ab = (kk & 1) ? A1 : A0;

            // ---- combine current gathers -> A tile (fp32 accum, bf16 store)
            v8bf r0, r1;
#pragma unroll
            for (int j = 0; j < 8; ++j) {
                r0[j] = (__bf16)(cw0[0] * (float)rv[0][j] + cw0[1] * (float)rv[1][j]
                               + cw0[2] * (float)rv[2][j] + cw0[3] * (float)rv[3][j]);
                r1[j] = (__bf16)(cw1[0] * (float)rv[4][j] + cw1[1] * (float)rv[5][j]
                               + cw1[2] * (float)rv[6][j] + cw1[3] * (float)rv[7][j]);
            }
            *(v8bf*)(Ab + prow * 40 + pcg * 8) = r0;
            *(v8bf*)(Ab + (prow + 64) * 40 + pcg * 8) = r1;

            // ---- prefetch next K-step's gathers (overlaps barrier + MFMA)
            if (c8 < 7) {
                const int cch = (c8 + 1) * 32 + pcg * 8;
#pragma unroll
                for (int t = 0; t < 4; ++t) {
                    rv[t]     = *(const v8bf*)(xb + cb0[t] + cch);
                    rv[4 + t] = *(const v8bf*)(xb + cb1[t] + cch);
                }
            }

            // ---- B frags direct from global (B^T layout)
            v8bf bfr[4];
#pragma unroll
            for (int nt = 0; nt < 4; ++nt)
                bfr[nt] = *(const v8bf*)(bp
                    + (size_t)(o0 + wn * 64 + nt * 16 + l15) * KG + kk * 32 + q * 8);

            __syncthreads();               // A(kk) visible; buffers alternate -> 1 barrier/step

            v8bf afr[4];
#pragma unroll
            for (int mt = 0; mt < 4; ++mt)
                afr[mt] = *(const v8bf*)(Ab + (wm * 64 + mt * 16 + l15) * 40 + q * 8);
#pragma unroll
            for (int mt = 0; mt < 4; ++mt)
#pragma unroll
                for (int nt = 0; nt < 4; ++nt)
                    acc[mt][nt] = __builtin_amdgcn_mfma_f32_16x16x32_bf16(
                        afr[mt], bfr[nt], acc[mt][nt], 0, 0, 0);
        }
    }

    __syncthreads();   // all LDS frag reads done; alias LDS for epilogue
    // ---- epilogue: per-wave 64x64 LDS transpose, coalesced fp32 atomicAdd
    float* epi = (float*)smem + wv * (64 * 20);
    const int pg = m0 + wm * 64 + lane;
    const int n_img = pg / SPIX;
    const int s_pix = pg - n_img * SPIX;
    float* outb = out + (size_t)n_img * COUT * SPIX + s_pix;

#pragma unroll
    for (int nt = 0; nt < 4; ++nt) {
        const float bv = (kz == 0) ? bias[o0 + wn * 64 + nt * 16 + l15] : 0.0f;
#pragma unroll
        for (int mt = 0; mt < 4; ++mt)
#pragma unroll
            for (int r = 0; r < 4; ++r)
                epi[(mt * 16 + q * 4 + r) * 20 + l15] = acc[mt][nt][r] + bv;
        __syncthreads();
#pragma unroll
        for (int c4 = 0; c4 < 4; ++c4) {
            v4f vv = *(const v4f*)(epi + lane * 20 + c4 * 4);
            const int ob = o0 + wn * 64 + nt * 16 + c4 * 4;
            atomicAdd(&outb[(size_t)(ob + 0) * SPIX], vv.x);
            atomicAdd(&outb[(size_t)(ob + 1) * SPIX], vv.y);
            atomicAdd(&outb[(size_t)(ob + 2) * SPIX], vv.z);
            atomicAdd(&outb[(size_t)(ob + 3) * SPIX], vv.w);
        }
        __syncthreads();
    }
}

// ---------- fallback (round-1 verified fp32 path, no workspace needed)
#define BM 64
#define BN 64
#define BKF 32
#define AST 68
#define BST 68
#define CST 65
__global__ __launch_bounds__(256) void mdcn_fallback(
    const float* __restrict__ xs, const float* __restrict__ offs,
    const float* __restrict__ msk, const float* __restrict__ wraw,
    const float* __restrict__ bias, float* __restrict__ out)
{
    __shared__ float smem[BKF * AST + BKF * BST];
    __shared__ int   sBase[4][BM];
    __shared__ float sWgt[4][BM];
    float (*At)[AST] = (float (*)[AST])smem;
    float (*Bt)[BST] = (float (*)[BST])(smem + BKF * AST);
    float (*Cs)[CST] = (float (*)[CST])smem;
    const int tid = threadIdx.x;
    const int m0 = blockIdx.x * BM;
    const int o0 = blockIdx.y * BN;
    const int n  = m0 / SPIX;
    const int s0 = m0 - n * SPIX;
    const int tx = tid & 15, ty = tid >> 4;
    float acc[4][4] = {};
    for (int k = 0; k < 9; ++k) {
        if (tid < BM) {
            const int s = s0 + tid;
            const int h = s / W_;
            const int w = s - h * W_;
            const int kY = k / 3, kX = k - kY * 3;
            const float dy = offs[(size_t)n * (18 * SPIX) + (size_t)(2 * k) * SPIX + s];
            const float dx = offs[(size_t)n * (18 * SPIX) + (size_t)(2 * k + 1) * SPIX + s];
            const float mk = msk[(size_t)n * (9 * SPIX) + (size_t)k * SPIX + s];
            const float py = dy + (float)(kY + h - 1);
            const float px = dx + (float)(kX + w - 1);
            const float fy0 = floorf(py), fx0 = floorf(px);
            const int y0 = (int)fy0, x0 = (int)fx0;
            const float wy1 = py - fy0, wx1 = px - fx0;
            const float wy0 = 1.0f - wy1, wx0 = 1.0f - wx1;
#pragma unroll
            for (int t = 0; t < 4; ++t) {
                const int yi = y0 + (t >> 1), xi = x0 + (t & 1);
                const bool valid = (yi >= 0) & (yi < H_) & (xi >= 0) & (xi < W_);
                const int yc = min(max(yi, 0), H_ - 1);
                const int xc = min(max(xi, 0), W_ - 1);
                float wt = ((t >> 1) ? wy1 : wy0) * ((t & 1) ? wx1 : wx0) * mk;
                sBase[t][tid] = n * (CIN * SPIX) + yc * W_ + xc;
                sWgt[t][tid] = valid ? wt : 0.0f;
            }
        }
        __syncthreads();
        for (int c0 = 0; c0 < CIN; c0 += BKF) {
#pragma unroll
            for (int i = 0; i < 8; ++i) {
                int idx = tid + i * 256;
                int row = idx >> 5, cc = idx & 31;
                int ce = (c0 + cc) * SPIX;
                At[cc][row] = sWgt[0][row] * xs[sBase[0][row] + ce]
                            + sWgt[1][row] * xs[sBase[1][row] + ce]
                            + sWgt[2][row] * xs[sBase[2][row] + ce]
                            + sWgt[3][row] * xs[sBase[3][row] + ce];
            }
#pragma unroll
            for (int i = 0; i < 8; ++i) {
                int idx = tid + i * 256;
                int kf = idx >> 6, o = idx & 63;
                Bt[kf][o] = wraw[(size_t)(o0 + o) * KG + (c0 + kf) * 9 + k];
            }
            __syncthreads();
#pragma unroll
            for (int kf = 0; kf < BKF; ++kf) {
                const float4 a = *(const float4*)&At[kf][ty * 4];
                const float4 b = *(const float4*)&Bt[kf][tx * 4];
                acc[0][0] = fmaf(a.x, b.x, acc[0][0]); acc[0][1] = fmaf(a.x, b.y, acc[0][1]);
                acc[0][2] = fmaf(a.x, b.z, acc[0][2]); acc[0][3] = fmaf(a.x, b.w, acc[0][3]);
                acc[1][0] = fmaf(a.y, b.x, acc[1][0]); acc[1][1] = fmaf(a.y, b.y, acc[1][1]);
                acc[1][2] = fmaf(a.y, b.z, acc[1][2]); acc[1][3] = fmaf(a.y, b.w, acc[1][3]);
                acc[2][0] = fmaf(a.z, b.x, acc[2][0]); acc[2][1] = fmaf(a.z, b.y, acc[2][1]);
                acc[2][2] = fmaf(a.z, b.z, acc[2][2]); acc[2][3] = fmaf(a.z, b.w, acc[2][3]);
                acc[3][0] = fmaf(a.w, b.x, acc[3][0]); acc[3][1] = fmaf(a.w, b.y, acc[3][1]);
                acc[3][2] = fmaf(a.w, b.z, acc[3][2]); acc[3][3] = fmaf(a.w, b.w, acc[3][3]);
            }
            __syncthreads();
        }
    }
#pragma unroll
    for (int i = 0; i < 4; ++i)
#pragma unroll
        for (int j = 0; j < 4; ++j)
            Cs[ty * 4 + i][tx * 4 + j] = acc[i][j] + bias[o0 + tx * 4 + j];
    __syncthreads();
    const int pix = tid & 63, ob = tid >> 6;
    float* outp = out + (size_t)n * COUT * SPIX + s0 + pix;
#pragma unroll
    for (int r = 0; r < 16; ++r) {
        int o = r * 4 + ob;
        outp[(size_t)(o0 + o) * SPIX] = Cs[pix][o];
    }
}

extern "C" void kernel_launch(void* const* d_in, const int* in_sizes, int n_in,
                              void* d_out, int out_size, void* d_ws, size_t ws_size,
                              hipStream_t stream) {
    const float* x    = (const float*)d_in[0];
    const float* offs = (const float*)d_in[1];
    const float* msk  = (const float*)d_in[2];
    const float* w    = (const float*)d_in[3];
    const float* bias = (const float*)d_in[4];
    float* out = (float*)d_out;

    const size_t xb_bytes = (size_t)NB * SPIX * CIN * sizeof(__bf16);   // 12.85 MB
    const size_t bp_bytes = (size_t)KG * COUT * sizeof(__bf16);         // 1.18 MB

    if (ws_size >= xb_bytes + bp_bytes) {
        __bf16* xb = (__bf16*)d_ws;
        __bf16* bp = (__bf16*)((char*)d_ws + xb_bytes);
        prep_x<<<dim3(49, 4, 8), 256, 0, stream>>>(x, xb);
        prep_w<<<dim3((COUT * KG + 255) / 256), 256, 0, stream>>>(w, bp);
        hipMemsetAsync(out, 0, (size_t)out_size * sizeof(float), stream);
        mdcn_mfma<<<dim3(MTOT / 128, COUT / 128, 2), 256, 0, stream>>>(
            xb, offs, msk, bp, bias, out);
    } else {
        mdcn_fallback<<<dim3(MTOT / BM, COUT / BN), 256, 0, stream>>>(
            x, offs, msk, w, bias, out);
    }
}